// Round 1
// baseline (431.208 us; speedup 1.0000x reference)
//
#include <hip/hip_runtime.h>

#define BATCH   1024
#define IDIM    256
#define ODIM    256
#define GRIDSZ  300

#define BM      256
#define BN      128
#define MT      4      // 1024/256
#define NT      2      // 256/128
#define KS_     32     // K-splits
#define IPW     8      // i-values per workgroup = 256/32
#define NSTEPS  160    // 2 (t) * 8 (il) * 10 (g-chunks of 32, 300 padded to 320)
#define APITCH  40     // 32 + 8 bf16 pad (LDS bank-conflict break)
#define INV2PI  0.15915494309189535f

typedef __attribute__((ext_vector_type(8))) short  short8;
typedef __attribute__((ext_vector_type(4))) float  f32x4;
typedef __attribute__((ext_vector_type(4))) unsigned int u32x4;

// RNE float->bf16 pair pack (a -> low16, b -> high16). Inputs are finite.
__device__ __forceinline__ unsigned pack2bf(float a, float b) {
  unsigned ua = __float_as_uint(a);
  unsigned ub = __float_as_uint(b);
  ua += 0x7fffu + ((ua >> 16) & 1u);
  ub += 0x7fffu + ((ub >> 16) & 1u);
  return (ua >> 16) | (ub & 0xffff0000u);
}

// Decode flat K-step index S -> (t, il, gs)
__device__ __forceinline__ void decodeS(int S, int& t, int& il, int& gs) {
  t  = (S >= 80) ? 1 : 0;
  int r = S - t * 80;
  il = r / 10;
  gs = r - il * 10;
}

// Compute this thread's 16 A-panel values for step S, packed to 8 dwords.
// A[b][k] = cos(x[b,i]*(g0+k+1)) for t=0, sin(...) for t=1 (0 in the g>=300 pad).
// sin(2*pi*f) == cos(2*pi*(f - 0.25)) -> single v_cos path, offset folded into the FMA.
__device__ __forceinline__ void computeA(const float* __restrict__ x, int S,
                                         int m, int ks, int ab, int ahalf,
                                         unsigned aw[8]) {
  int t, il, gs; decodeS(S, t, il, gs);
  const int i  = ks * IPW + il;
  const int g0 = gs * 32;
  const float xr   = x[(m * BM + ab) * IDIM + i] * INV2PI;   // L1-resident (reused 10 steps)
  const float offs = t ? -0.25f : 0.0f;
  const float kb   = (float)(g0 + ahalf * 16 + 1);
  float v[16];
#pragma unroll
  for (int p = 0; p < 16; ++p) {
    float pr = __builtin_fmaf(xr, kb + (float)p, offs);
    float fr = __builtin_amdgcn_fractf(pr);          // exact range reduction -> cos domain safe
    v[p] = __builtin_amdgcn_cosf(fr);
  }
  if (gs == 9) {                                     // wave-uniform, 1/10 steps: zero the pad
#pragma unroll
    for (int p = 0; p < 16; ++p)
      if (g0 + ahalf * 16 + p >= GRIDSZ) v[p] = 0.0f;
  }
#pragma unroll
  for (int p = 0; p < 8; ++p) aw[p] = pack2bf(v[2 * p], v[2 * p + 1]);
}

// Prefetch this thread's 8 B-panel floats for step S (two float4, g-clamped in-bounds).
__device__ __forceinline__ void loadB(const float* __restrict__ fc, int S,
                                      int ks, int n, int bj, int bq,
                                      f32x4& p0, f32x4& p1) {
  int t, il, gs; decodeS(S, t, il, gs);
  const int i = ks * IPW + il;
  int ga = gs * 32 + bq * 8;
  int gb = ga + 4;
  ga = (ga > 296) ? 296 : ga;    // pad region: clamp inside allocation; A-side zeros kill it
  gb = (gb > 296) ? 296 : gb;
  const float* base = fc + ((t * ODIM + n * BN + bj) * IDIM + i) * GRIDSZ;
  p0 = *(const f32x4*)(base + ga);
  p1 = *(const f32x4*)(base + gb);
}

__global__ void init_out(const float* __restrict__ bias, float* __restrict__ out) {
  const int idx = blockIdx.x * 256 + threadIdx.x;
  out[idx] = bias[idx & (ODIM - 1)];
}

__global__ __launch_bounds__(512, 2) void fkan_gemm(
    const float* __restrict__ x, const float* __restrict__ fc,
    float* __restrict__ out) {
  __shared__ alignas(16) short A_lds[BM * APITCH];   // 20480 B
  __shared__ alignas(16) short B_lds[BN * APITCH];   // 10240 B

  const int tid = threadIdx.x;
  const int id  = blockIdx.x;
  // XCD swizzle (blockIdx % 8 heuristic): the 4 m-siblings of one (n,ks) share an XCD-L2,
  // so B replication across M-tiles is served by L2, HBM fetch ~= unique 157 MB.
  const int xcd = id & 7;
  const int q   = id >> 3;
  const int m   = q & 3;
  const int h   = ((q >> 2) << 3) | xcd;   // 0..63
  const int ks  = h >> 1;
  const int n   = h & 1;

  const int wave = tid >> 6, lane = tid & 63;
  const int wm = wave >> 1, wn = wave & 1;       // 4x2 wave grid, 64x64 tile per wave
  const int fr = lane & 15, fq = lane >> 4;

  const int ab    = tid >> 1;    // A staging: row 0..255
  const int ahalf = tid & 1;     //            k-half (16 values)
  const int bj    = tid & 127;   // B staging: row 0..127
  const int bq    = tid >> 7;    //            k-quarter (8 values)

  f32x4 acc[4][4];
#pragma unroll
  for (int a_ = 0; a_ < 4; ++a_)
#pragma unroll
    for (int b_ = 0; b_ < 4; ++b_)
      acc[a_][b_] = (f32x4){0.f, 0.f, 0.f, 0.f};

  unsigned aw[8];
  f32x4 pb[2][2];
  computeA(x, 0, m, ks, ab, ahalf, aw);
  loadB(fc, 0, ks, n, bj, bq, pb[0][0], pb[0][1]);   // 2-deep register prefetch:
  loadB(fc, 1, ks, n, bj, bq, pb[1][0], pb[1][1]);   // full iteration to hide HBM latency

#pragma unroll 2
  for (int S = 0; S < NSTEPS; ++S) {
    // ---- stage panels to LDS ----
    u32x4 w0 = {aw[0], aw[1], aw[2], aw[3]};
    u32x4 w1 = {aw[4], aw[5], aw[6], aw[7]};
    *(u32x4*)&A_lds[ab * APITCH + ahalf * 16]     = w0;
    *(u32x4*)&A_lds[ab * APITCH + ahalf * 16 + 8] = w1;
    f32x4 q0 = pb[S & 1][0], q1 = pb[S & 1][1];
    u32x4 wb = { pack2bf(q0.x, q0.y), pack2bf(q0.z, q0.w),
                 pack2bf(q1.x, q1.y), pack2bf(q1.z, q1.w) };
    *(u32x4*)&B_lds[bj * APITCH + bq * 8] = wb;
    __syncthreads();

    // ---- MFMA ----
    short8 aF[4], bF[4];
#pragma unroll
    for (int tI = 0; tI < 4; ++tI)
      aF[tI] = *(const short8*)&A_lds[(wm * 64 + tI * 16 + fr) * APITCH + fq * 8];
#pragma unroll
    for (int tJ = 0; tJ < 4; ++tJ)
      bF[tJ] = *(const short8*)&B_lds[(wn * 64 + tJ * 16 + fr) * APITCH + fq * 8];
#pragma unroll
    for (int tI = 0; tI < 4; ++tI)
#pragma unroll
      for (int tJ = 0; tJ < 4; ++tJ)
        acc[tI][tJ] = __builtin_amdgcn_mfma_f32_16x16x32_bf16(aF[tI], bF[tJ], acc[tI][tJ], 0, 0, 0);

    // ---- next-step work between the barriers: trans-pipe sincos overlaps matrix pipe ----
    if (S + 1 < NSTEPS) computeA(x, S + 1, m, ks, ab, ahalf, aw);
    if (S + 2 < NSTEPS) loadB(fc, S + 2, ks, n, bj, bq, pb[S & 1][0], pb[S & 1][1]);
    __syncthreads();
  }

  // ---- epilogue: C/D layout col=lane&15, row=(lane>>4)*4+r [m89]; K-splits via HW fp32 atomics
  const int ob = m * BM + wm * 64 + fq * 4;
  const int oj = n * BN + wn * 64 + fr;
#pragma unroll
  for (int tI = 0; tI < 4; ++tI)
#pragma unroll
    for (int tJ = 0; tJ < 4; ++tJ) {
      float* dst = out + (ob + tI * 16) * ODIM + (oj + tJ * 16);
#pragma unroll
      for (int rr = 0; rr < 4; ++rr)
        unsafeAtomicAdd(dst + rr * ODIM, acc[tI][tJ][rr]);
    }
}

extern "C" void kernel_launch(void* const* d_in, const int* in_sizes, int n_in,
                              void* d_out, int out_size, void* d_ws, size_t ws_size,
                              hipStream_t stream) {
  const float* x    = (const float*)d_in[0];
  const float* fc   = (const float*)d_in[1];
  const float* bias = (const float*)d_in[2];
  float* out = (float*)d_out;

  init_out<<<dim3(BATCH * ODIM / 256), dim3(256), 0, stream>>>(bias, out);
  fkan_gemm<<<dim3(MT * NT * KS_), dim3(512), 0, stream>>>(x, fc, out);
}

// Round 2
// 367.766 us; speedup vs baseline: 1.1725x; 1.1725x over previous
//
#include <hip/hip_runtime.h>

#define BATCH   1024
#define IDIM    256
#define ODIM    256
#define GRIDSZ  300

#define BM      128
#define BN      128
#define MT      8      // 1024/BM
#define NT      2      // 256/BN
#define KS_     64     // K-splits over i
#define IPW     4      // i per block = IDIM/KS_
#define GS_STEPS 19    // g-chunks of 16 (k=1..304, tail zero-padded)
#define NSTEPS  (IPW*GS_STEPS)
#define AP      40     // LDS pitch in shorts: 32 k + 8 pad (80 B, 5 quads -> conflict-free b128)
#define INV2PI  0.15915494309189535f

typedef __attribute__((ext_vector_type(8))) short  short8;
typedef __attribute__((ext_vector_type(4))) float  f32x4;
typedef __attribute__((ext_vector_type(4))) unsigned int u32x4;

// bf16 pair pack: round-half-up (add 0x8000) + v_perm byte select. 3 VALU ops.
// low16 = c (k even = cos plane), high16 = s (k odd = sin plane).
__device__ __forceinline__ unsigned pk(float c, float s) {
  unsigned a = __float_as_uint(c) + 0x8000u;
  unsigned b = __float_as_uint(s) + 0x8000u;
  return __builtin_amdgcn_perm(b, a, 0x07060302u);
}

// (c,s) *= (C,S)  — 2 mul + 2 fma
__device__ __forceinline__ void rot(float& c, float& s, float C, float S) {
  float t1 = s * S;
  float t2 = c * S;
  float cn = __builtin_fmaf(c, C, -t1);
  s = __builtin_fmaf(s, C, t2);
  c = cn;
}

// cos/sin of 2*pi*rev via v_fract + v_cos (revolutions; exact range reduction)
__device__ __forceinline__ void cossin(float rev, float& c, float& s) {
  c = __builtin_amdgcn_cosf(__builtin_amdgcn_fractf(rev));
  s = __builtin_amdgcn_cosf(__builtin_amdgcn_fractf(rev - 0.25f));
}

__global__ void init_out(const float* __restrict__ bias, float* __restrict__ out) {
  const int idx = blockIdx.x * 256 + threadIdx.x;
  out[idx] = bias[idx & (ODIM - 1)];
}

__global__ __launch_bounds__(256, 3) void fkan_gemm(
    const float* __restrict__ x, const float* __restrict__ fc,
    float* __restrict__ out) {
  __shared__ alignas(16) short A_lds[BM * AP];   // 10240 B
  __shared__ alignas(16) short B_lds[BN * AP];   // 10240 B

  const int tid = threadIdx.x;
  const int id  = blockIdx.x;
  // swizzle: the 8 m-siblings of one (n,ks) have ids differing by 8 -> same XCD (id%8),
  // so the shared B slice is fetched once per XCD-L2.
  const int z = id & 7, q = id >> 3;
  const int m = q & 7, r = q >> 3;          // m 0..7, r 0..15
  const int n  = z & 1;
  const int ks = (z >> 1) | (r << 2);       // 0..63

  const int wave = tid >> 6, lane = tid & 63;
  const int wm = wave >> 1, wn = wave & 1;  // 2x2 wave grid, 64x64 tile/wave
  const int fr = lane & 15, fq = lane >> 4;

  const int rA = tid >> 1;   // panel row 0..127 (A-batch row and B-j row)
  const int hB = tid & 1;    // k-half: p in [hB*8, hB*8+8)

  const float* xrow = x + (size_t)(m * BM + rA) * IDIM + ks * IPW;
  const float* b0 = fc + ((size_t)(n * BN + rA) * IDIM + ks * IPW) * GRIDSZ + hB * 8;
  const float* b1 = b0 + (size_t)ODIM * IDIM * GRIDSZ;

  short* Awr = &A_lds[rA * AP + hB * 16];
  short* Bwr = &B_lds[rA * AP + hB * 16];
  const short* Ard = &A_lds[(wm * 64 + fr) * AP + fq * 8];
  const short* Brd = &B_lds[(wn * 64 + fr) * AP + fq * 8];

  f32x4 acc[4][4];
#pragma unroll
  for (int a_ = 0; a_ < 4; ++a_)
#pragma unroll
    for (int b_ = 0; b_ < 4; ++b_)
      acc[a_][b_] = (f32x4){0.f, 0.f, 0.f, 0.f};

  // ---- prologue: A recurrence seed + emit for step (il=0, gs=0), B load+pack
  float xr = xrow[0] * INV2PI;
  float r1c, r1s, r16c, r16s, sc, ss;
  cossin(xr, r1c, r1s);               // rotation by delta-k = 1
  cossin(xr * 16.0f, r16c, r16s);     // rotation by delta-k = 16 (per gs-step)
  cossin(xr * (float)(hB * 8 + 1), sc, ss);   // state at k = hB*8+1
  unsigned ad[8];
  {
    float c = sc, s = ss;
    ad[0] = pk(c, s);
#pragma unroll
    for (int u = 1; u < 8; ++u) { rot(c, s, r1c, r1s); ad[u] = pk(c, s); }
  }
  unsigned bw[8];
  {
    f32x4 L0a = *(const f32x4*)(b0);
    f32x4 L0b = *(const f32x4*)(b0 + 4);
    f32x4 L1a = *(const f32x4*)(b1);
    f32x4 L1b = *(const f32x4*)(b1 + 4);
    bw[0] = pk(L0a.x, L1a.x); bw[1] = pk(L0a.y, L1a.y);
    bw[2] = pk(L0a.z, L1a.z); bw[3] = pk(L0a.w, L1a.w);
    bw[4] = pk(L0b.x, L1b.x); bw[5] = pk(L0b.y, L1b.y);
    bw[6] = pk(L0b.z, L1b.z); bw[7] = pk(L0b.w, L1b.w);
  }

  int il = 0, gs = 0, soff = 0;

  for (int S = 0; S < NSTEPS; ++S) {
    // ---- stage current step's panels (K interleaved: k = 2p + t)
    *(u32x4*)Awr       = (u32x4){ad[0], ad[1], ad[2], ad[3]};
    *(u32x4*)(Awr + 8) = (u32x4){ad[4], ad[5], ad[6], ad[7]};
    *(u32x4*)Bwr       = (u32x4){bw[0], bw[1], bw[2], bw[3]};
    *(u32x4*)(Bwr + 8) = (u32x4){bw[4], bw[5], bw[6], bw[7]};
    __syncthreads();

    // ---- next-step bookkeeping (block-uniform -> SGPR) + B prefetch issue
    int gsn = gs + 1, iln = il;
    if (gsn == GS_STEPS) { gsn = 0; iln++; }
    const bool newil = (gsn == 0);
    if (iln >= IPW) iln = 0;                       // dummy wrap on final iteration
    const int soffn = newil ? iln * GRIDSZ : soff + 16;
    // gs=18,h=1: second quad would read g=300..303 -> clamp to 296 (A zeros kill it)
    const int o2 = soffn + ((((gsn == 18) ? 1 : 0) & hB) ? 0 : 4);
    f32x4 L0a = *(const f32x4*)(b0 + soffn);
    f32x4 L0b = *(const f32x4*)(b0 + o2);
    f32x4 L1a = *(const f32x4*)(b1 + soffn);
    f32x4 L1b = *(const f32x4*)(b1 + o2);

    // ---- MFMA (aF all 4 live; bF one at a time to cap VGPR peak)
    short8 aF[4];
#pragma unroll
    for (int tI = 0; tI < 4; ++tI) aF[tI] = *(const short8*)(Ard + tI * 16 * AP);
#pragma unroll
    for (int tJ = 0; tJ < 4; ++tJ) {
      short8 bF = *(const short8*)(Brd + tJ * 16 * AP);
#pragma unroll
      for (int tI = 0; tI < 4; ++tI)
        acc[tI][tJ] = __builtin_amdgcn_mfma_f32_16x16x32_bf16(aF[tI], bF, acc[tI][tJ], 0, 0, 0);
    }

    // ---- compute next A between the barriers (overlaps matrix pipe)
    if (newil) {
      xr = xrow[iln] * INV2PI;
      cossin(xr, r1c, r1s);
      cossin(xr * 16.0f, r16c, r16s);
      cossin(xr * (float)(hB * 8 + 1), sc, ss);
    } else {
      rot(sc, ss, r16c, r16s);    // advance state by delta-g = 16
    }
    {
      float c = sc, s = ss;
      ad[0] = pk(c, s);
#pragma unroll
      for (int u = 1; u < 8; ++u) { rot(c, s, r1c, r1s); ad[u] = pk(c, s); }
    }
    if (((gsn == 18) ? 1 : 0) & hB) { ad[4] = 0u; ad[5] = 0u; ad[6] = 0u; ad[7] = 0u; }

    // ---- pack next B (vmcnt wait lands here, after MFMA+A-compute)
    bw[0] = pk(L0a.x, L1a.x); bw[1] = pk(L0a.y, L1a.y);
    bw[2] = pk(L0a.z, L1a.z); bw[3] = pk(L0a.w, L1a.w);
    bw[4] = pk(L0b.x, L1b.x); bw[5] = pk(L0b.y, L1b.y);
    bw[6] = pk(L0b.z, L1b.z); bw[7] = pk(L0b.w, L1b.w);

    il = iln; gs = gsn; soff = soffn;
    __syncthreads();
  }

  // ---- epilogue: C/D layout col=lane&15, row=(lane>>4)*4+reg [m89]; K-split HW fp32 atomics
  const int ob = m * BM + wm * 64 + fq * 4;
  const int oj = n * BN + wn * 64 + fr;
#pragma unroll
  for (int tI = 0; tI < 4; ++tI)
#pragma unroll
    for (int tJ = 0; tJ < 4; ++tJ) {
      float* dst = out + (size_t)(ob + tI * 16) * ODIM + (oj + tJ * 16);
#pragma unroll
      for (int rr = 0; rr < 4; ++rr)
        unsafeAtomicAdd(dst + rr * ODIM, acc[tI][tJ][rr]);
    }
}

extern "C" void kernel_launch(void* const* d_in, const int* in_sizes, int n_in,
                              void* d_out, int out_size, void* d_ws, size_t ws_size,
                              hipStream_t stream) {
  const float* x    = (const float*)d_in[0];
  const float* fc   = (const float*)d_in[1];
  const float* bias = (const float*)d_in[2];
  float* out = (float*)d_out;

  init_out<<<dim3(BATCH * ODIM / 256), dim3(256), 0, stream>>>(bias, out);
  fkan_gemm<<<dim3(MT * NT * KS_), dim3(256), 0, stream>>>(x, fc, out);
}